// Round 10
// baseline (261.540 us; speedup 1.0000x reference)
//
#include <hip/hip_runtime.h>
#include <hip/hip_bf16.h>

typedef unsigned short u16;
typedef unsigned int   u32;
typedef __attribute__((ext_vector_type(8))) short bf16x8;
typedef __attribute__((ext_vector_type(4))) float f32x4;

__device__ __forceinline__ u16 f2bf(float f) {
  u32 u = __float_as_uint(f);
  u32 r = u + 0x7fffu + ((u >> 16) & 1u);
  return (u16)(r >> 16);
}
__device__ __forceinline__ float bflo(u32 u) { return __uint_as_float(u << 16); }
__device__ __forceinline__ float bfhi(u32 u) { return __uint_as_float(u & 0xffff0000u); }
// pack (hi16(b)<<16)|hi16(a) in one v_perm (truncation-to-bf16; bias cancels
// in softmax normalization, ~0.4% rel elsewhere — noise vs 0.109 threshold)
__device__ __forceinline__ u32 packhi(float a, float b) {
  return __builtin_amdgcn_perm(__float_as_uint(b), __float_as_uint(a), 0x07060302u);
}

// ---------------------------------------------------------------------------
// Kernel 1: avgpool 2x2 + Q/K/V 1x1-conv projections via MFMA.
// grid 1024 x 256 (4 waves). side = blockIdx&1 (0: rgb->Q, 1: freq->K,V).
// Q,K stored [b][n][64] bf16; V stored [b][64][n] bf16.
// Q pre-scaled by hid^-0.5 * log2(e) so k_attn can use exp2 directly.
// Store path = r8 direct stores (r9's LDS-staged variant was -3.4us: two
// extra barriers serialize the block for a tiny store phase — reverted).
// ---------------------------------------------------------------------------
__global__ __launch_bounds__(256, 4) void k_qkv(
    const float* __restrict__ rgb, const float* __restrict__ freq,
    const float* __restrict__ wq, const float* __restrict__ bq,
    const float* __restrict__ wk, const float* __restrict__ bk,
    const float* __restrict__ wv, const float* __restrict__ bv,
    u16* __restrict__ Qo, u16* __restrict__ Ko, u16* __restrict__ Vo)
{
  __shared__ __align__(16) u16 sm[3 * 4608];
  u16* X  = sm;             // [64][72] pooled input tokens
  u16* W0 = sm + 4608;      // [64][72] wq or wk
  u16* W1 = sm + 9216;      // [64][72] wv (side 1 only)

  const int t    = threadIdx.x;
  const int side = blockIdx.x & 1;
  const int seg  = blockIdx.x >> 1;       // 0..511
  const int idx0 = seg * 64;              // global token base (b*4096+n)
  const int bb   = idx0 >> 12;
  const int n0   = idx0 & 4095;
  const int h    = n0 >> 6;               // pooled row (uniform per block)
  const float* src = side ? freq : rgb;

  // ---- stage pooled X: thread = (token-pair, channel-granule), float4 ----
  const size_t sbase = (size_t)bb * 64 * 16384 + (size_t)(2 * h) * 128;
  {
    const int tokp = t & 31;              // token pair 0..31 (lane-consecutive)
    const int grp  = t >> 5;              // channel granule 0..7
    const float* p0 = src + sbase + 4 * tokp + (size_t)(grp * 8) * 16384;
    u32 pk0[4], pk1[4];
#pragma unroll
    for (int c = 0; c < 8; c += 2) {
      const float* pa = p0 + (size_t)c * 16384;
      float4 a0 = *(const float4*)pa;
      float4 a1 = *(const float4*)(pa + 128);
      float t0a = 0.25f * ((a0.x + a0.y) + (a1.x + a1.y));
      float t1a = 0.25f * ((a0.z + a0.w) + (a1.z + a1.w));
      const float* pb = pa + 16384;
      float4 c0 = *(const float4*)pb;
      float4 c1 = *(const float4*)(pb + 128);
      float t0b = 0.25f * ((c0.x + c0.y) + (c1.x + c1.y));
      float t1b = 0.25f * ((c0.z + c0.w) + (c1.z + c1.w));
      pk0[c >> 1] = (u32)f2bf(t0a) | ((u32)f2bf(t0b) << 16);
      pk1[c >> 1] = (u32)f2bf(t1a) | ((u32)f2bf(t1b) << 16);
    }
    uint4 qv0; qv0.x = pk0[0]; qv0.y = pk0[1]; qv0.z = pk0[2]; qv0.w = pk0[3];
    uint4 qv1; qv1.x = pk1[0]; qv1.y = pk1[1]; qv1.z = pk1[2]; qv1.w = pk1[3];
    *(uint4*)&X[(2 * tokp) * 72 + grp * 8] = qv0;
    *(uint4*)&X[(2 * tokp + 1) * 72 + grp * 8] = qv1;
  }
  // ---- stage weights, float4-coalesced: thread -> (o = t>>2, c0 = (t&3)*16)
  {
    const int o = t >> 2, c0 = (t & 3) << 4;
    const float4* p4 = (const float4*)((side ? wk : wq) + o * 64 + c0);
    float4 f0 = p4[0], f1 = p4[1], f2 = p4[2], f3 = p4[3];
    uint4 qa, qb;
    qa.x = (u32)f2bf(f0.x) | ((u32)f2bf(f0.y) << 16);
    qa.y = (u32)f2bf(f0.z) | ((u32)f2bf(f0.w) << 16);
    qa.z = (u32)f2bf(f1.x) | ((u32)f2bf(f1.y) << 16);
    qa.w = (u32)f2bf(f1.z) | ((u32)f2bf(f1.w) << 16);
    qb.x = (u32)f2bf(f2.x) | ((u32)f2bf(f2.y) << 16);
    qb.y = (u32)f2bf(f2.z) | ((u32)f2bf(f2.w) << 16);
    qb.z = (u32)f2bf(f3.x) | ((u32)f2bf(f3.y) << 16);
    qb.w = (u32)f2bf(f3.z) | ((u32)f2bf(f3.w) << 16);
    *(uint4*)&W0[o * 72 + c0] = qa;
    *(uint4*)&W0[o * 72 + c0 + 8] = qb;
    if (side) {
      const float4* v4 = (const float4*)(wv + o * 64 + c0);
      float4 g0 = v4[0], g1 = v4[1], g2 = v4[2], g3 = v4[3];
      qa.x = (u32)f2bf(g0.x) | ((u32)f2bf(g0.y) << 16);
      qa.y = (u32)f2bf(g0.z) | ((u32)f2bf(g0.w) << 16);
      qa.z = (u32)f2bf(g1.x) | ((u32)f2bf(g1.y) << 16);
      qa.w = (u32)f2bf(g1.z) | ((u32)f2bf(g1.w) << 16);
      qb.x = (u32)f2bf(g2.x) | ((u32)f2bf(g2.y) << 16);
      qb.y = (u32)f2bf(g2.z) | ((u32)f2bf(g2.w) << 16);
      qb.z = (u32)f2bf(g3.x) | ((u32)f2bf(g3.y) << 16);
      qb.w = (u32)f2bf(g3.z) | ((u32)f2bf(g3.w) << 16);
      *(uint4*)&W1[o * 72 + c0] = qa;
      *(uint4*)&W1[o * 72 + c0 + 8] = qb;
    }
  }
  __syncthreads();

  const int lane = t & 63, w = t >> 6;
  const int l15 = lane & 15, qd = lane >> 4;
  const int tb = w * 16;                  // wave's 16 tokens

  bf16x8 af0 = *(const bf16x8*)&X[(tb + l15) * 72 + qd * 8];
  bf16x8 af1 = *(const bf16x8*)&X[(tb + l15) * 72 + 32 + qd * 8];

  // ---- Q (side 0) / K (side 1): A = X (rows tok), B = W0 (cols o) ----
  f32x4 acc[4];
#pragma unroll
  for (int nt = 0; nt < 4; ++nt) {
    bf16x8 b0 = *(const bf16x8*)&W0[(nt * 16 + l15) * 72 + qd * 8];
    bf16x8 b1 = *(const bf16x8*)&W0[(nt * 16 + l15) * 72 + 32 + qd * 8];
    f32x4 a = {0.f, 0.f, 0.f, 0.f};
    a = __builtin_amdgcn_mfma_f32_16x16x32_bf16(af0, b0, a, 0, 0, 0);
    a = __builtin_amdgcn_mfma_f32_16x16x32_bf16(af1, b1, a, 0, 0, 0);
    acc[nt] = a;
  }
  {
    const float* bias0 = side ? bk : bq;
    // Q scale = hid^-0.5 * log2(e); K unscaled
    const float sc = side ? 1.f : 0.18033688f;
    u16* dst0 = side ? Ko : Qo;
#pragma unroll
    for (int nt = 0; nt < 4; ++nt) {
      float bia = bias0[nt * 16 + l15];
#pragma unroll
      for (int e = 0; e < 4; ++e) {
        int tok = idx0 + tb + qd * 4 + e;     // D row = token
        dst0[(size_t)tok * 64 + nt * 16 + l15] = f2bf((acc[nt][e] + bia) * sc);
      }
    }
  }

  if (side) {
    // ---- V: A = Wv (rows c), B = X (cols tok) -> D = V^T directly ----
    f32x4 accv[4];
#pragma unroll
    for (int ct = 0; ct < 4; ++ct) {
      bf16x8 a0 = *(const bf16x8*)&W1[(ct * 16 + l15) * 72 + qd * 8];
      bf16x8 a1 = *(const bf16x8*)&W1[(ct * 16 + l15) * 72 + 32 + qd * 8];
      f32x4 a = {0.f, 0.f, 0.f, 0.f};
      a = __builtin_amdgcn_mfma_f32_16x16x32_bf16(a0, af0, a, 0, 0, 0);
      a = __builtin_amdgcn_mfma_f32_16x16x32_bf16(a1, af1, a, 0, 0, 0);
      accv[ct] = a;
    }
#pragma unroll
    for (int ct = 0; ct < 4; ++ct) {
#pragma unroll
      for (int e = 0; e < 4; ++e) {
        int c = ct * 16 + qd * 4 + e;          // D row = V channel
        float v = accv[ct][e] + bv[c];
        Vo[((size_t)(bb * 64 + c)) * 4096 + n0 + tb + l15] = f2bf(v);
      }
    }
  }
}

// ---------------------------------------------------------------------------
// Kernel 2: attention + fused output-conv/BN epilogue, barrier-free K-loop.
// grid (8 b, 64 qtile) x 256 threads = 4 independent waves.
// Structure = r0/r7 verified optimum (64-q tile, (256,2), batched loads).
// r10: K register PING-PONG (kfA/kfB, static names) — tile t+1's 8 K loads
// issue before tile t's PV, hiding the per-tile L2 round-trip (~300-400cyc)
// that was the last exposed latency. r1's dbuf spilled from per-call address
// recomputation; here addresses are loop-carried pointers with compile-time
// fragment offsets (+4 regs), and one sched_barrier(0) per prefetch stops
// the r6-style load-sinking. V loads moved to the top of each half-tile so
// they land under QK+exp. Live ~150 arch + 64 acc < 256 cap -> no spill.
// Epilogue: Y^T = BNaffine(Wo·Z) channel-outer via Pb staging + coalesced
// uint4 stores (r9, verified).
// ---------------------------------------------------------------------------
__global__ __launch_bounds__(256, 2) void k_attn(
    const u16* __restrict__ Qg, const u16* __restrict__ Kg,
    const u16* __restrict__ Vg,
    const float* __restrict__ wo, const float* __restrict__ bo,
    const float* __restrict__ gam, const float* __restrict__ bet,
    const float* __restrict__ mean, const float* __restrict__ var,
    u16* __restrict__ Ya)
{
  __shared__ __align__(16) u16 Pb[4 * 4608];   // per-wave [64 q][72] P / partial-Z / Y staging
  __shared__ __align__(16) u16 Wl[4608];       // Wo [64 o][72]
  __shared__ __align__(16) u16 Zc[4608];       // combined Z [64 q][72]
  __shared__ float lb[256];                    // [wave][64 q] denominators
  __shared__ float Afs[64], Bfs[64];           // BN affine per o

  const int b  = blockIdx.x;                   // batch -> XCD affinity
  const int q0 = blockIdx.y * 64;
  const int t  = threadIdx.x;
  const int lane = t & 63, w = t >> 6;
  const int l15 = lane & 15, qd = lane >> 4;
  u16* P = Pb + w * 4608;

  // ---- stage Wo (bf16, rounded) + BN affine coefficients ----
  {
    const int o = t >> 2, c0 = (t & 3) << 4;
    const float4* p4 = (const float4*)(wo + o * 64 + c0);
    float4 f0 = p4[0], f1 = p4[1], f2 = p4[2], f3 = p4[3];
    uint4 qa, qb;
    qa.x = (u32)f2bf(f0.x) | ((u32)f2bf(f0.y) << 16);
    qa.y = (u32)f2bf(f0.z) | ((u32)f2bf(f0.w) << 16);
    qa.z = (u32)f2bf(f1.x) | ((u32)f2bf(f1.y) << 16);
    qa.w = (u32)f2bf(f1.z) | ((u32)f2bf(f1.w) << 16);
    qb.x = (u32)f2bf(f2.x) | ((u32)f2bf(f2.y) << 16);
    qb.y = (u32)f2bf(f2.z) | ((u32)f2bf(f2.w) << 16);
    qb.z = (u32)f2bf(f3.x) | ((u32)f2bf(f3.y) << 16);
    qb.w = (u32)f2bf(f3.z) | ((u32)f2bf(f3.w) << 16);
    *(uint4*)&Wl[o * 72 + c0] = qa;
    *(uint4*)&Wl[o * 72 + c0 + 8] = qb;
    if (t < 64) {
      float A = gam[t] * __frsqrt_rn(var[t] + 1e-5f);
      Afs[t] = A;
      Bfs[t] = (bo[t] - mean[t]) * A + bet[t];
    }
  }

  // ---- Q fragments (B-operand, scale*log2e pre-folded) ----
  bf16x8 qf[4][2];
#pragma unroll
  for (int qt = 0; qt < 4; ++qt) {
    const u16* p = Qg + ((size_t)(b * 4096 + q0 + qt * 16 + l15)) * 64 + qd * 8;
    qf[qt][0] = *(const bf16x8*)p;
    qf[qt][1] = *(const bf16x8*)(p + 32);
  }

  f32x4 zacc[4][4];                            // [ct][qt]
#pragma unroll
  for (int i = 0; i < 4; ++i)
#pragma unroll
    for (int j = 0; j < 4; ++j) {
      f32x4 z = {0.f, 0.f, 0.f, 0.f};
      zacc[i][j] = z;
    }
  float lacc[4] = {0.f, 0.f, 0.f, 0.f};

  // fragment offsets are compile-time constants off loop-carried pointers:
  // K: mt*16 rows x 64ch = 1024 u16/mt; advance 64 rows = 4096 u16/tile.
  // V: ct*16 rows x 4096 = 65536 u16/ct; advance 64 keys = 64 u16/tile.
#define LOADK(DST, P_) do {                                                   \
    DST[0][0] = *(const bf16x8*)(P_);          DST[0][1] = *(const bf16x8*)((P_) + 32);   \
    DST[1][0] = *(const bf16x8*)((P_) + 1024); DST[1][1] = *(const bf16x8*)((P_) + 1056); \
    DST[2][0] = *(const bf16x8*)((P_) + 2048); DST[2][1] = *(const bf16x8*)((P_) + 2080); \
    DST[3][0] = *(const bf16x8*)((P_) + 3072); DST[3][1] = *(const bf16x8*)((P_) + 3104); \
  } while (0)
#define LOADV(DST, P_) do {                                                   \
    DST[0][0] = *(const bf16x8*)(P_);            DST[0][1] = *(const bf16x8*)((P_) + 32);     \
    DST[1][0] = *(const bf16x8*)((P_) + 65536);  DST[1][1] = *(const bf16x8*)((P_) + 65568);  \
    DST[2][0] = *(const bf16x8*)((P_) + 131072); DST[2][1] = *(const bf16x8*)((P_) + 131104); \
    DST[3][0] = *(const bf16x8*)((P_) + 196608); DST[3][1] = *(const bf16x8*)((P_) + 196640); \
  } while (0)
#define QK_PHASE(KF) do {                                                     \
    _Pragma("unroll")                                                         \
    for (int qt = 0; qt < 4; ++qt) {                                          \
      _Pragma("unroll")                                                       \
      for (int mt = 0; mt < 4; ++mt) {                                        \
        f32x4 a = {0.f, 0.f, 0.f, 0.f};                                       \
        __builtin_amdgcn_s_setprio(1);                                        \
        a = __builtin_amdgcn_mfma_f32_16x16x32_bf16(KF[mt][0], qf[qt][0], a, 0, 0, 0); \
        a = __builtin_amdgcn_mfma_f32_16x16x32_bf16(KF[mt][1], qf[qt][1], a, 0, 0, 0); \
        __builtin_amdgcn_s_setprio(0);                                        \
        float p0 = __builtin_amdgcn_exp2f(a[0]);                              \
        float p1 = __builtin_amdgcn_exp2f(a[1]);                              \
        float p2 = __builtin_amdgcn_exp2f(a[2]);                              \
        float p3 = __builtin_amdgcn_exp2f(a[3]);                              \
        lacc[qt] += (p0 + p1) + (p2 + p3);                                    \
        uint2 pw;                                                             \
        pw.x = packhi(p0, p1);                                                \
        pw.y = packhi(p2, p3);                                                \
        *(uint2*)&P[(qt * 16 + l15) * 72 + mt * 16 + qd * 4] = pw;            \
      }                                                                       \
    }                                                                         \
  } while (0)
#define PV_PHASE(VF) do {                                                     \
    _Pragma("unroll")                                                         \
    for (int qt = 0; qt < 4; ++qt) {                                          \
      bf16x8 pf0 = *(const bf16x8*)&P[(qt * 16 + l15) * 72 + qd * 8];         \
      bf16x8 pf1 = *(const bf16x8*)&P[(qt * 16 + l15) * 72 + 32 + qd * 8];    \
      __builtin_amdgcn_s_setprio(1);                                          \
      _Pragma("unroll")                                                       \
      for (int ct = 0; ct < 4; ++ct) {                                        \
        zacc[ct][qt] = __builtin_amdgcn_mfma_f32_16x16x32_bf16(VF[ct][0], pf0, zacc[ct][qt], 0, 0, 0); \
        zacc[ct][qt] = __builtin_amdgcn_mfma_f32_16x16x32_bf16(VF[ct][1], pf1, zacc[ct][qt], 0, 0, 0); \
      }                                                                       \
      __builtin_amdgcn_s_setprio(0);                                          \
    }                                                                         \
  } while (0)

  const u16* kp = Kg + ((size_t)(b * 4096 + w * 1024 + l15)) * 64 + qd * 8;
  const u16* vp = Vg + ((size_t)(b * 64 + l15)) * 4096 + w * 1024 + qd * 8;
  bf16x8 kfA[4][2], kfB[4][2], vf[4][2];

  LOADK(kfA, kp); kp += 4096;
  for (int it = 0; it < 8; ++it) {
    // -- even tile: compute kfA, prefetch kfB --
    LOADV(vf, vp); vp += 64;
    QK_PHASE(kfA);
    LOADK(kfB, kp); kp += 4096;
    __builtin_amdgcn_sched_barrier(0);   // pin prefetch issue before PV
    PV_PHASE(vf);
    // -- odd tile: compute kfB, prefetch kfA --
    LOADV(vf, vp); vp += 64;
    QK_PHASE(kfB);
    if (it < 7) {
      LOADK(kfA, kp); kp += 4096;
      __builtin_amdgcn_sched_barrier(0);
    }
    PV_PHASE(vf);
  }
#undef LOADK
#undef LOADV
#undef QK_PHASE
#undef PV_PHASE

  // ---- epilogue: denominators + unnormalized partial Z ([q][c] bf16) ----
#pragma unroll
  for (int qt = 0; qt < 4; ++qt) {
    float l = lacc[qt];
    l += __shfl_xor(l, 16);
    l += __shfl_xor(l, 32);
    lb[w * 64 + qt * 16 + l15] = l;   // all quads write same value: benign
  }
#pragma unroll
  for (int qt = 0; qt < 4; ++qt)
#pragma unroll
    for (int ct = 0; ct < 4; ++ct) {
      uint2 pw;
      pw.x = packhi(zacc[ct][qt][0], zacc[ct][qt][1]);
      pw.y = packhi(zacc[ct][qt][2], zacc[ct][qt][3]);
      *(uint2*)&P[(qt * 16 + l15) * 72 + ct * 16 + qd * 4] = pw;
    }
  __syncthreads();

  // ---- combine 4 key-splits + normalize -> Zc[q][72] bf16 ----
  {
    const u32* Pu = (const u32*)Pb;            // wave stride 2304 u32, row 36
    u32* Zu = (u32*)Zc;
#pragma unroll
    for (int i = 0; i < 8; ++i) {
      int cell = i * 256 + t;                  // 0..2047
      int q = cell >> 5, cu = cell & 31;
      float s0 = 0.f, s1 = 0.f;
#pragma unroll
      for (int ww = 0; ww < 4; ++ww) {
        u32 v = Pu[ww * 2304 + q * 36 + cu];
        s0 += bflo(v);
        s1 += bfhi(v);
      }
      float inv = 1.f / (lb[q] + lb[64 + q] + lb[128 + q] + lb[192 + q]);
      Zu[q * 36 + cu] = packhi(s0 * inv, s1 * inv);
    }
  }
  __syncthreads();

  // ---- Y^T = affine(Wo · Z): A = Wl (rows o), B = Zc (rows q) ----
  // D row (qd*4+e) = o, D col (l15) = q. Stage into Pb (dead), then
  // 2x uint4/thread coalesced store to channel-outer Ya[b][o][n].
  {
    u16* Ys = Pb;                              // [64 o][72 q] staging
    bf16x8 af0 = *(const bf16x8*)&Zc[(w * 16 + l15) * 72 + qd * 8];
    bf16x8 af1 = *(const bf16x8*)&Zc[(w * 16 + l15) * 72 + 32 + qd * 8];
#pragma unroll
    for (int nt = 0; nt < 4; ++nt) {
      bf16x8 b0 = *(const bf16x8*)&Wl[(nt * 16 + l15) * 72 + qd * 8];
      bf16x8 b1 = *(const bf16x8*)&Wl[(nt * 16 + l15) * 72 + 32 + qd * 8];
      f32x4 y = {0.f, 0.f, 0.f, 0.f};
      y = __builtin_amdgcn_mfma_f32_16x16x32_bf16(b0, af0, y, 0, 0, 0);
      y = __builtin_amdgcn_mfma_f32_16x16x32_bf16(b1, af1, y, 0, 0, 0);
#pragma unroll
      for (int e = 0; e < 4; ++e) {
        const int o = nt * 16 + qd * 4 + e;
        float v = y[e] * Afs[o] + Bfs[o];
        Ys[o * 72 + w * 16 + l15] = (u16)(__float_as_uint(v) >> 16);
      }
    }
  }
  __syncthreads();
  {
    const int o = t >> 2, c4 = (t & 3) << 4;
    uint4 y0 = *(const uint4*)&Pb[o * 72 + c4];
    uint4 y1 = *(const uint4*)&Pb[o * 72 + c4 + 8];
    u16* d = Ya + ((size_t)(b * 64 + o)) * 4096 + q0;
    *(uint4*)&d[c4] = y0;
    *(uint4*)&d[c4 + 8] = y1;
  }
}

// ---------------------------------------------------------------------------
// Kernel 3: bilinear 2x upsample of channel-outer Ya + LeakyReLU + residual.
// grid 8192 x 256: thread = (b, o, i, j-quad of 4 consecutive j).
// rgb read + out write are one float4 each (wave: 1KB contiguous).
// Ya corners: 6 coalesced u32 loads. No LDS, 8 waves/SIMD.
// ---------------------------------------------------------------------------
__global__ __launch_bounds__(256, 8) void k_out(
    const u16* __restrict__ Ya, const float* __restrict__ rgb,
    float* __restrict__ out)
{
  const int tid = blockIdx.x * 256 + threadIdx.x;  // 0..2097151
  const int g = tid & 31;                          // j-quad (j = 4g..4g+3)
  const int i = (tid >> 5) & 127;
  const int o = (tid >> 12) & 63;
  const int b = tid >> 18;

  float ys = fmaxf(0.5f * (float)i - 0.25f, 0.f);
  int   y0 = (int)ys;
  float wy = ys - (float)y0;
  int   y1 = min(y0 + 1, 63);

  const u32* Yw = (const u32*)(Ya + ((size_t)(b * 64 + o)) * 4096);
  const int base0 = y0 * 32, base1 = y1 * 32;
  const int gm = (g == 0) ? 0 : g - 1;
  const int gp = (g == 31) ? 31 : g + 1;

  u32 tm = Yw[base0 + gm], t0 = Yw[base0 + g], tp = Yw[base0 + gp];
  u32 bm = Yw[base1 + gm], b0w = Yw[base1 + g], bp = Yw[base1 + gp];

  const float iw = 1.f - wy;
  // row-interpolated values at x = 2g-1, 2g, 2g+1, 2g+2
  float r_m1 = iw * bfhi(tm) + wy * bfhi(bm);
  float r_0  = iw * bflo(t0) + wy * bflo(b0w);
  float r_1  = iw * bfhi(t0) + wy * bfhi(b0w);
  float r_2  = iw * bflo(tp) + wy * bflo(bp);

  float v0 = (g == 0)  ? r_0 : 0.25f * r_m1 + 0.75f * r_0;
  float v1 = 0.75f * r_0 + 0.25f * r_1;
  float v2 = 0.25f * r_0 + 0.75f * r_1;
  float v3 = (g == 31) ? r_1 : 0.75f * r_1 + 0.25f * r_2;

  v0 = (v0 >= 0.f) ? v0 : 0.2f * v0;
  v1 = (v1 >= 0.f) ? v1 : 0.2f * v1;
  v2 = (v2 >= 0.f) ? v2 : 0.2f * v2;
  v3 = (v3 >= 0.f) ? v3 : 0.2f * v3;

  const size_t pix = ((size_t)((b * 64 + o) * 128 + i)) * 128 + g * 4;
  float4 rv = *(const float4*)(rgb + pix);
  float4 ov;
  ov.x = rv.x + v0;
  ov.y = rv.y + v1;
  ov.z = rv.z + v2;
  ov.w = rv.w + v3;
  *(float4*)(out + pix) = ov;
}

// ---------------------------------------------------------------------------
extern "C" void kernel_launch(void* const* d_in, const int* in_sizes, int n_in,
                              void* d_out, int out_size, void* d_ws, size_t ws_size,
                              hipStream_t stream) {
  (void)in_sizes; (void)n_in; (void)out_size; (void)ws_size;
  const float* rgb  = (const float*)d_in[0];
  const float* freq = (const float*)d_in[1];
  const float* wq   = (const float*)d_in[2];
  const float* bq   = (const float*)d_in[3];
  const float* wk   = (const float*)d_in[4];
  const float* bk   = (const float*)d_in[5];
  const float* wv   = (const float*)d_in[6];
  const float* bv   = (const float*)d_in[7];
  const float* wo   = (const float*)d_in[8];
  const float* bo   = (const float*)d_in[9];
  const float* gam  = (const float*)d_in[10];
  const float* bet  = (const float*)d_in[11];
  const float* mean = (const float*)d_in[12];
  const float* var  = (const float*)d_in[13];

  char* ws = (char*)d_ws;
  u16* Qw = (u16*)(ws);               // 8*4096*64 bf16 = 4 MiB
  u16* Kw = (u16*)(ws + 4194304);     // 4 MiB
  u16* Vw = (u16*)(ws + 8388608);     // 4 MiB (transposed [b][c][n])
  u16* Yw = (u16*)(ws + 12582912);    // 4 MiB  Ya[b][64 o][4096 n] (ch-outer)

  k_qkv<<<dim3(1024), dim3(256), 0, stream>>>(rgb, freq, wq, bq, wk, bk, wv, bv,
                                              Qw, Kw, Vw);
  k_attn<<<dim3(8, 64), dim3(256), 0, stream>>>(Qw, Kw, Vw, wo, bo, gam, bet,
                                                mean, var, Yw);
  k_out<<<dim3(8192), dim3(256), 0, stream>>>(Yw, rgb, (float*)d_out);
}

// Round 11
// 200.208 us; speedup vs baseline: 1.3063x; 1.3063x over previous
//
#include <hip/hip_runtime.h>
#include <hip/hip_bf16.h>

typedef unsigned short u16;
typedef unsigned int   u32;
typedef __attribute__((ext_vector_type(8))) short bf16x8;
typedef __attribute__((ext_vector_type(4))) float f32x4;

__device__ __forceinline__ u16 f2bf(float f) {
  u32 u = __float_as_uint(f);
  u32 r = u + 0x7fffu + ((u >> 16) & 1u);
  return (u16)(r >> 16);
}
__device__ __forceinline__ float bflo(u32 u) { return __uint_as_float(u << 16); }
__device__ __forceinline__ float bfhi(u32 u) { return __uint_as_float(u & 0xffff0000u); }
// pack (hi16(b)<<16)|hi16(a) in one v_perm (truncation-to-bf16; bias cancels
// in softmax normalization, ~0.4% rel elsewhere — noise vs 0.109 threshold)
__device__ __forceinline__ u32 packhi(float a, float b) {
  return __builtin_amdgcn_perm(__float_as_uint(b), __float_as_uint(a), 0x07060302u);
}

// ---------------------------------------------------------------------------
// Kernel 1: avgpool 2x2 + Q/K/V 1x1-conv projections via MFMA.
// grid 1024 x 256 (4 waves). side = blockIdx&1 (0: rgb->Q, 1: freq->K,V).
// Q,K stored [b][n][64] bf16; V stored [b][64][n] bf16.
// Q pre-scaled by hid^-0.5 * log2(e) so k_attn can use exp2 directly.
// float4 staging (r8); direct stores (r9's LDS-staged stores were -3.4us).
// ---------------------------------------------------------------------------
__global__ __launch_bounds__(256, 4) void k_qkv(
    const float* __restrict__ rgb, const float* __restrict__ freq,
    const float* __restrict__ wq, const float* __restrict__ bq,
    const float* __restrict__ wk, const float* __restrict__ bk,
    const float* __restrict__ wv, const float* __restrict__ bv,
    u16* __restrict__ Qo, u16* __restrict__ Ko, u16* __restrict__ Vo)
{
  __shared__ __align__(16) u16 sm[3 * 4608];
  u16* X  = sm;             // [64][72] pooled input tokens
  u16* W0 = sm + 4608;      // [64][72] wq or wk
  u16* W1 = sm + 9216;      // [64][72] wv (side 1 only)

  const int t    = threadIdx.x;
  const int side = blockIdx.x & 1;
  const int seg  = blockIdx.x >> 1;       // 0..511
  const int idx0 = seg * 64;              // global token base (b*4096+n)
  const int bb   = idx0 >> 12;
  const int n0   = idx0 & 4095;
  const int h    = n0 >> 6;               // pooled row (uniform per block)
  const float* src = side ? freq : rgb;

  // ---- stage pooled X: thread = (token-pair, channel-granule), float4 ----
  const size_t sbase = (size_t)bb * 64 * 16384 + (size_t)(2 * h) * 128;
  {
    const int tokp = t & 31;              // token pair 0..31 (lane-consecutive)
    const int grp  = t >> 5;              // channel granule 0..7
    const float* p0 = src + sbase + 4 * tokp + (size_t)(grp * 8) * 16384;
    u32 pk0[4], pk1[4];
#pragma unroll
    for (int c = 0; c < 8; c += 2) {
      const float* pa = p0 + (size_t)c * 16384;
      float4 a0 = *(const float4*)pa;
      float4 a1 = *(const float4*)(pa + 128);
      float t0a = 0.25f * ((a0.x + a0.y) + (a1.x + a1.y));
      float t1a = 0.25f * ((a0.z + a0.w) + (a1.z + a1.w));
      const float* pb = pa + 16384;
      float4 c0 = *(const float4*)pb;
      float4 c1 = *(const float4*)(pb + 128);
      float t0b = 0.25f * ((c0.x + c0.y) + (c1.x + c1.y));
      float t1b = 0.25f * ((c0.z + c0.w) + (c1.z + c1.w));
      pk0[c >> 1] = (u32)f2bf(t0a) | ((u32)f2bf(t0b) << 16);
      pk1[c >> 1] = (u32)f2bf(t1a) | ((u32)f2bf(t1b) << 16);
    }
    uint4 qv0; qv0.x = pk0[0]; qv0.y = pk0[1]; qv0.z = pk0[2]; qv0.w = pk0[3];
    uint4 qv1; qv1.x = pk1[0]; qv1.y = pk1[1]; qv1.z = pk1[2]; qv1.w = pk1[3];
    *(uint4*)&X[(2 * tokp) * 72 + grp * 8] = qv0;
    *(uint4*)&X[(2 * tokp + 1) * 72 + grp * 8] = qv1;
  }
  // ---- stage weights, float4-coalesced: thread -> (o = t>>2, c0 = (t&3)*16)
  {
    const int o = t >> 2, c0 = (t & 3) << 4;
    const float4* p4 = (const float4*)((side ? wk : wq) + o * 64 + c0);
    float4 f0 = p4[0], f1 = p4[1], f2 = p4[2], f3 = p4[3];
    uint4 qa, qb;
    qa.x = (u32)f2bf(f0.x) | ((u32)f2bf(f0.y) << 16);
    qa.y = (u32)f2bf(f0.z) | ((u32)f2bf(f0.w) << 16);
    qa.z = (u32)f2bf(f1.x) | ((u32)f2bf(f1.y) << 16);
    qa.w = (u32)f2bf(f1.z) | ((u32)f2bf(f1.w) << 16);
    qb.x = (u32)f2bf(f2.x) | ((u32)f2bf(f2.y) << 16);
    qb.y = (u32)f2bf(f2.z) | ((u32)f2bf(f2.w) << 16);
    qb.z = (u32)f2bf(f3.x) | ((u32)f2bf(f3.y) << 16);
    qb.w = (u32)f2bf(f3.z) | ((u32)f2bf(f3.w) << 16);
    *(uint4*)&W0[o * 72 + c0] = qa;
    *(uint4*)&W0[o * 72 + c0 + 8] = qb;
    if (side) {
      const float4* v4 = (const float4*)(wv + o * 64 + c0);
      float4 g0 = v4[0], g1 = v4[1], g2 = v4[2], g3 = v4[3];
      qa.x = (u32)f2bf(g0.x) | ((u32)f2bf(g0.y) << 16);
      qa.y = (u32)f2bf(g0.z) | ((u32)f2bf(g0.w) << 16);
      qa.z = (u32)f2bf(g1.x) | ((u32)f2bf(g1.y) << 16);
      qa.w = (u32)f2bf(g1.z) | ((u32)f2bf(g1.w) << 16);
      qb.x = (u32)f2bf(g2.x) | ((u32)f2bf(g2.y) << 16);
      qb.y = (u32)f2bf(g2.z) | ((u32)f2bf(g2.w) << 16);
      qb.z = (u32)f2bf(g3.x) | ((u32)f2bf(g3.y) << 16);
      qb.w = (u32)f2bf(g3.z) | ((u32)f2bf(g3.w) << 16);
      *(uint4*)&W1[o * 72 + c0] = qa;
      *(uint4*)&W1[o * 72 + c0 + 8] = qb;
    }
  }
  __syncthreads();

  const int lane = t & 63, w = t >> 6;
  const int l15 = lane & 15, qd = lane >> 4;
  const int tb = w * 16;                  // wave's 16 tokens

  bf16x8 af0 = *(const bf16x8*)&X[(tb + l15) * 72 + qd * 8];
  bf16x8 af1 = *(const bf16x8*)&X[(tb + l15) * 72 + 32 + qd * 8];

  // ---- Q (side 0) / K (side 1): A = X (rows tok), B = W0 (cols o) ----
  f32x4 acc[4];
#pragma unroll
  for (int nt = 0; nt < 4; ++nt) {
    bf16x8 b0 = *(const bf16x8*)&W0[(nt * 16 + l15) * 72 + qd * 8];
    bf16x8 b1 = *(const bf16x8*)&W0[(nt * 16 + l15) * 72 + 32 + qd * 8];
    f32x4 a = {0.f, 0.f, 0.f, 0.f};
    a = __builtin_amdgcn_mfma_f32_16x16x32_bf16(af0, b0, a, 0, 0, 0);
    a = __builtin_amdgcn_mfma_f32_16x16x32_bf16(af1, b1, a, 0, 0, 0);
    acc[nt] = a;
  }
  {
    const float* bias0 = side ? bk : bq;
    // Q scale = hid^-0.5 * log2(e); K unscaled
    const float sc = side ? 1.f : 0.18033688f;
    u16* dst0 = side ? Ko : Qo;
#pragma unroll
    for (int nt = 0; nt < 4; ++nt) {
      float bia = bias0[nt * 16 + l15];
#pragma unroll
      for (int e = 0; e < 4; ++e) {
        int tok = idx0 + tb + qd * 4 + e;     // D row = token
        dst0[(size_t)tok * 64 + nt * 16 + l15] = f2bf((acc[nt][e] + bia) * sc);
      }
    }
  }

  if (side) {
    // ---- V: A = Wv (rows c), B = X (cols tok) -> D = V^T directly ----
    f32x4 accv[4];
#pragma unroll
    for (int ct = 0; ct < 4; ++ct) {
      bf16x8 a0 = *(const bf16x8*)&W1[(ct * 16 + l15) * 72 + qd * 8];
      bf16x8 a1 = *(const bf16x8*)&W1[(ct * 16 + l15) * 72 + 32 + qd * 8];
      f32x4 a = {0.f, 0.f, 0.f, 0.f};
      a = __builtin_amdgcn_mfma_f32_16x16x32_bf16(a0, af0, a, 0, 0, 0);
      a = __builtin_amdgcn_mfma_f32_16x16x32_bf16(a1, af1, a, 0, 0, 0);
      accv[ct] = a;
    }
#pragma unroll
    for (int ct = 0; ct < 4; ++ct) {
#pragma unroll
      for (int e = 0; e < 4; ++e) {
        int c = ct * 16 + qd * 4 + e;          // D row = V channel
        float v = accv[ct][e] + bv[c];
        Vo[((size_t)(bb * 64 + c)) * 4096 + n0 + tb + l15] = f2bf(v);
      }
    }
  }
}

// ---------------------------------------------------------------------------
// Kernel 2: attention + fused output-conv/BN epilogue, barrier-free K-loop.
// grid (8 b, 64 qtile) x 256 threads = 4 independent waves.
// FROZEN at the r9 verified optimum (72.9us, VGPR 120, no spill).
// Ledger of failed perturbations (do NOT retry):
//   r1/r10: K/V register double-buffer -> spill (95/135us; any dbuf exceeds
//           the 128-arch-VGPR allocation quantum, even pointer-carried)
//   r3:     512-thr blocks -> launch_bounds cap 64, spill (133us)
//   r5:     serialized loads @56 regs, 4 waves/SIMD -> 126us (TLP < ILP)
//   r6:     32-q tile -> compiler sinks loads, de-batches (129us)
// Wave w: key-split w (keys w*1024..+1024, 16 tiles of 64), all 64 block-q.
// No-max softmax (exp2; log2e folded into Q); partials combine additively.
// Epilogue: combine+normalize Z in LDS, Y^T = BNaffine(Wo·Z) channel-outer
// via Pb staging + coalesced uint4 stores (r9, verified).
// ---------------------------------------------------------------------------
__global__ __launch_bounds__(256, 2) void k_attn(
    const u16* __restrict__ Qg, const u16* __restrict__ Kg,
    const u16* __restrict__ Vg,
    const float* __restrict__ wo, const float* __restrict__ bo,
    const float* __restrict__ gam, const float* __restrict__ bet,
    const float* __restrict__ mean, const float* __restrict__ var,
    u16* __restrict__ Ya)
{
  __shared__ __align__(16) u16 Pb[4 * 4608];   // per-wave [64 q][72] P / partial-Z / Y staging
  __shared__ __align__(16) u16 Wl[4608];       // Wo [64 o][72]
  __shared__ __align__(16) u16 Zc[4608];       // combined Z [64 q][72]
  __shared__ float lb[256];                    // [wave][64 q] denominators
  __shared__ float Afs[64], Bfs[64];           // BN affine per o

  const int b  = blockIdx.x;                   // batch -> XCD affinity
  const int q0 = blockIdx.y * 64;
  const int t  = threadIdx.x;
  const int lane = t & 63, w = t >> 6;
  const int l15 = lane & 15, qd = lane >> 4;
  u16* P = Pb + w * 4608;

  // ---- stage Wo (bf16, rounded) + BN affine coefficients ----
  {
    const int o = t >> 2, c0 = (t & 3) << 4;
    const float4* p4 = (const float4*)(wo + o * 64 + c0);
    float4 f0 = p4[0], f1 = p4[1], f2 = p4[2], f3 = p4[3];
    uint4 qa, qb;
    qa.x = (u32)f2bf(f0.x) | ((u32)f2bf(f0.y) << 16);
    qa.y = (u32)f2bf(f0.z) | ((u32)f2bf(f0.w) << 16);
    qa.z = (u32)f2bf(f1.x) | ((u32)f2bf(f1.y) << 16);
    qa.w = (u32)f2bf(f1.z) | ((u32)f2bf(f1.w) << 16);
    qb.x = (u32)f2bf(f2.x) | ((u32)f2bf(f2.y) << 16);
    qb.y = (u32)f2bf(f2.z) | ((u32)f2bf(f2.w) << 16);
    qb.z = (u32)f2bf(f3.x) | ((u32)f2bf(f3.y) << 16);
    qb.w = (u32)f2bf(f3.z) | ((u32)f2bf(f3.w) << 16);
    *(uint4*)&Wl[o * 72 + c0] = qa;
    *(uint4*)&Wl[o * 72 + c0 + 8] = qb;
    if (t < 64) {
      float A = gam[t] * __frsqrt_rn(var[t] + 1e-5f);
      Afs[t] = A;
      Bfs[t] = (bo[t] - mean[t]) * A + bet[t];
    }
  }

  // ---- Q fragments (B-operand, scale*log2e pre-folded) ----
  bf16x8 qf[4][2];
#pragma unroll
  for (int qt = 0; qt < 4; ++qt) {
    const u16* p = Qg + ((size_t)(b * 4096 + q0 + qt * 16 + l15)) * 64 + qd * 8;
    qf[qt][0] = *(const bf16x8*)p;
    qf[qt][1] = *(const bf16x8*)(p + 32);
  }

  f32x4 zacc[4][4];                            // [ct][qt]
#pragma unroll
  for (int i = 0; i < 4; ++i)
#pragma unroll
    for (int j = 0; j < 4; ++j) {
      f32x4 z = {0.f, 0.f, 0.f, 0.f};
      zacc[i][j] = z;
    }
  float lacc[4] = {0.f, 0.f, 0.f, 0.f};

  for (int tile = 0; tile < 16; ++tile) {
    const int n0 = w * 1024 + tile * 64;

    // batch all K+V loads at tile top; other resident wave's softmax hides them
    bf16x8 kf[4][2], vf[4][2];
#pragma unroll
    for (int mt = 0; mt < 4; ++mt) {
      const u16* p = Kg + ((size_t)(b * 4096 + n0 + mt * 16 + l15)) * 64 + qd * 8;
      kf[mt][0] = *(const bf16x8*)p;
      kf[mt][1] = *(const bf16x8*)(p + 32);
    }
#pragma unroll
    for (int ct = 0; ct < 4; ++ct) {
      const u16* p = Vg + ((size_t)(b * 64 + ct * 16 + l15)) * 4096 + n0 + qd * 8;
      vf[ct][0] = *(const bf16x8*)p;
      vf[ct][1] = *(const bf16x8*)(p + 32);
    }

    // ---- S^T = K·Q^T, exp2, pack P[q][key] (perm-truncated bf16) ----
#pragma unroll
    for (int qt = 0; qt < 4; ++qt) {
#pragma unroll
      for (int mt = 0; mt < 4; ++mt) {
        f32x4 a = {0.f, 0.f, 0.f, 0.f};
        __builtin_amdgcn_s_setprio(1);
        a = __builtin_amdgcn_mfma_f32_16x16x32_bf16(kf[mt][0], qf[qt][0], a, 0, 0, 0);
        a = __builtin_amdgcn_mfma_f32_16x16x32_bf16(kf[mt][1], qf[qt][1], a, 0, 0, 0);
        __builtin_amdgcn_s_setprio(0);
        float p0 = __builtin_amdgcn_exp2f(a[0]);
        float p1 = __builtin_amdgcn_exp2f(a[1]);
        float p2 = __builtin_amdgcn_exp2f(a[2]);
        float p3 = __builtin_amdgcn_exp2f(a[3]);
        lacc[qt] += (p0 + p1) + (p2 + p3);
        uint2 pw;
        pw.x = packhi(p0, p1);
        pw.y = packhi(p2, p3);
        *(uint2*)&P[(qt * 16 + l15) * 72 + mt * 16 + qd * 4] = pw;
      }
    }
    // ---- Z^T += V^T · P^T ----
#pragma unroll
    for (int qt = 0; qt < 4; ++qt) {
      bf16x8 pf0 = *(const bf16x8*)&P[(qt * 16 + l15) * 72 + qd * 8];
      bf16x8 pf1 = *(const bf16x8*)&P[(qt * 16 + l15) * 72 + 32 + qd * 8];
      __builtin_amdgcn_s_setprio(1);
#pragma unroll
      for (int ct = 0; ct < 4; ++ct) {
        zacc[ct][qt] = __builtin_amdgcn_mfma_f32_16x16x32_bf16(vf[ct][0], pf0, zacc[ct][qt], 0, 0, 0);
        zacc[ct][qt] = __builtin_amdgcn_mfma_f32_16x16x32_bf16(vf[ct][1], pf1, zacc[ct][qt], 0, 0, 0);
      }
      __builtin_amdgcn_s_setprio(0);
    }
  }

  // ---- epilogue: denominators + unnormalized partial Z ([q][c] bf16) ----
#pragma unroll
  for (int qt = 0; qt < 4; ++qt) {
    float l = lacc[qt];
    l += __shfl_xor(l, 16);
    l += __shfl_xor(l, 32);
    lb[w * 64 + qt * 16 + l15] = l;   // all quads write same value: benign
  }
#pragma unroll
  for (int qt = 0; qt < 4; ++qt)
#pragma unroll
    for (int ct = 0; ct < 4; ++ct) {
      uint2 pw;
      pw.x = packhi(zacc[ct][qt][0], zacc[ct][qt][1]);
      pw.y = packhi(zacc[ct][qt][2], zacc[ct][qt][3]);
      *(uint2*)&P[(qt * 16 + l15) * 72 + ct * 16 + qd * 4] = pw;
    }
  __syncthreads();

  // ---- combine 4 key-splits + normalize -> Zc[q][72] bf16 ----
  {
    const u32* Pu = (const u32*)Pb;            // wave stride 2304 u32, row 36
    u32* Zu = (u32*)Zc;
#pragma unroll
    for (int i = 0; i < 8; ++i) {
      int cell = i * 256 + t;                  // 0..2047
      int q = cell >> 5, cu = cell & 31;
      float s0 = 0.f, s1 = 0.f;
#pragma unroll
      for (int ww = 0; ww < 4; ++ww) {
        u32 v = Pu[ww * 2304 + q * 36 + cu];
        s0 += bflo(v);
        s1 += bfhi(v);
      }
      float inv = 1.f / (lb[q] + lb[64 + q] + lb[128 + q] + lb[192 + q]);
      Zu[q * 36 + cu] = packhi(s0 * inv, s1 * inv);
    }
  }
  __syncthreads();

  // ---- Y^T = affine(Wo · Z): A = Wl (rows o), B = Zc (rows q) ----
  // D row (qd*4+e) = o, D col (l15) = q. Stage into Pb (dead), then
  // 2x uint4/thread coalesced store to channel-outer Ya[b][o][n].
  {
    u16* Ys = Pb;                              // [64 o][72 q] staging
    bf16x8 af0 = *(const bf16x8*)&Zc[(w * 16 + l15) * 72 + qd * 8];
    bf16x8 af1 = *(const bf16x8*)&Zc[(w * 16 + l15) * 72 + 32 + qd * 8];
#pragma unroll
    for (int nt = 0; nt < 4; ++nt) {
      bf16x8 b0 = *(const bf16x8*)&Wl[(nt * 16 + l15) * 72 + qd * 8];
      bf16x8 b1 = *(const bf16x8*)&Wl[(nt * 16 + l15) * 72 + 32 + qd * 8];
      f32x4 y = {0.f, 0.f, 0.f, 0.f};
      y = __builtin_amdgcn_mfma_f32_16x16x32_bf16(b0, af0, y, 0, 0, 0);
      y = __builtin_amdgcn_mfma_f32_16x16x32_bf16(b1, af1, y, 0, 0, 0);
#pragma unroll
      for (int e = 0; e < 4; ++e) {
        const int o = nt * 16 + qd * 4 + e;
        float v = y[e] * Afs[o] + Bfs[o];
        Ys[o * 72 + w * 16 + l15] = (u16)(__float_as_uint(v) >> 16);
      }
    }
  }
  __syncthreads();
  {
    const int o = t >> 2, c4 = (t & 3) << 4;
    uint4 y0 = *(const uint4*)&Pb[o * 72 + c4];
    uint4 y1 = *(const uint4*)&Pb[o * 72 + c4 + 8];
    u16* d = Ya + ((size_t)(b * 64 + o)) * 4096 + q0;
    *(uint4*)&d[c4] = y0;
    *(uint4*)&d[c4 + 8] = y1;
  }
}

// ---------------------------------------------------------------------------
// Kernel 3: bilinear 2x upsample of channel-outer Ya + LeakyReLU + residual.
// grid 8192 x 256: thread = (b, o, i, j-quad of 4 consecutive j).
// rgb read + out write are one float4 each (wave: 1KB contiguous).
// Ya corners: 6 coalesced u32 loads. No LDS, 8 waves/SIMD.
// ---------------------------------------------------------------------------
__global__ __launch_bounds__(256, 8) void k_out(
    const u16* __restrict__ Ya, const float* __restrict__ rgb,
    float* __restrict__ out)
{
  const int tid = blockIdx.x * 256 + threadIdx.x;  // 0..2097151
  const int g = tid & 31;                          // j-quad (j = 4g..4g+3)
  const int i = (tid >> 5) & 127;
  const int o = (tid >> 12) & 63;
  const int b = tid >> 18;

  float ys = fmaxf(0.5f * (float)i - 0.25f, 0.f);
  int   y0 = (int)ys;
  float wy = ys - (float)y0;
  int   y1 = min(y0 + 1, 63);

  const u32* Yw = (const u32*)(Ya + ((size_t)(b * 64 + o)) * 4096);
  const int base0 = y0 * 32, base1 = y1 * 32;
  const int gm = (g == 0) ? 0 : g - 1;
  const int gp = (g == 31) ? 31 : g + 1;

  u32 tm = Yw[base0 + gm], t0 = Yw[base0 + g], tp = Yw[base0 + gp];
  u32 bm = Yw[base1 + gm], b0w = Yw[base1 + g], bp = Yw[base1 + gp];

  const float iw = 1.f - wy;
  // row-interpolated values at x = 2g-1, 2g, 2g+1, 2g+2
  float r_m1 = iw * bfhi(tm) + wy * bfhi(bm);
  float r_0  = iw * bflo(t0) + wy * bflo(b0w);
  float r_1  = iw * bfhi(t0) + wy * bfhi(b0w);
  float r_2  = iw * bflo(tp) + wy * bflo(bp);

  float v0 = (g == 0)  ? r_0 : 0.25f * r_m1 + 0.75f * r_0;
  float v1 = 0.75f * r_0 + 0.25f * r_1;
  float v2 = 0.25f * r_0 + 0.75f * r_1;
  float v3 = (g == 31) ? r_1 : 0.75f * r_1 + 0.25f * r_2;

  v0 = (v0 >= 0.f) ? v0 : 0.2f * v0;
  v1 = (v1 >= 0.f) ? v1 : 0.2f * v1;
  v2 = (v2 >= 0.f) ? v2 : 0.2f * v2;
  v3 = (v3 >= 0.f) ? v3 : 0.2f * v3;

  const size_t pix = ((size_t)((b * 64 + o) * 128 + i)) * 128 + g * 4;
  float4 rv = *(const float4*)(rgb + pix);
  float4 ov;
  ov.x = rv.x + v0;
  ov.y = rv.y + v1;
  ov.z = rv.z + v2;
  ov.w = rv.w + v3;
  *(float4*)(out + pix) = ov;
}

// ---------------------------------------------------------------------------
extern "C" void kernel_launch(void* const* d_in, const int* in_sizes, int n_in,
                              void* d_out, int out_size, void* d_ws, size_t ws_size,
                              hipStream_t stream) {
  (void)in_sizes; (void)n_in; (void)out_size; (void)ws_size;
  const float* rgb  = (const float*)d_in[0];
  const float* freq = (const float*)d_in[1];
  const float* wq   = (const float*)d_in[2];
  const float* bq   = (const float*)d_in[3];
  const float* wk   = (const float*)d_in[4];
  const float* bk   = (const float*)d_in[5];
  const float* wv   = (const float*)d_in[6];
  const float* bv   = (const float*)d_in[7];
  const float* wo   = (const float*)d_in[8];
  const float* bo   = (const float*)d_in[9];
  const float* gam  = (const float*)d_in[10];
  const float* bet  = (const float*)d_in[11];
  const float* mean = (const float*)d_in[12];
  const float* var  = (const float*)d_in[13];

  char* ws = (char*)d_ws;
  u16* Qw = (u16*)(ws);               // 8*4096*64 bf16 = 4 MiB
  u16* Kw = (u16*)(ws + 4194304);     // 4 MiB
  u16* Vw = (u16*)(ws + 8388608);     // 4 MiB (transposed [b][c][n])
  u16* Yw = (u16*)(ws + 12582912);    // 4 MiB  Ya[b][64 o][4096 n] (ch-outer)

  k_qkv<<<dim3(1024), dim3(256), 0, stream>>>(rgb, freq, wq, bq, wk, bk, wv, bv,
                                              Qw, Kw, Vw);
  k_attn<<<dim3(8, 64), dim3(256), 0, stream>>>(Qw, Kw, Vw, wo, bo, gam, bet,
                                                mean, var, Yw);
  k_out<<<dim3(8192), dim3(256), 0, stream>>>(Yw, rgb, (float*)d_out);
}